// Round 3
// baseline (3527.445 us; speedup 1.0000x reference)
//
#include <hip/hip_runtime.h>
#include <hip/hip_bf16.h>

#define DEV __device__ __forceinline__
using bf16 = __hip_bfloat16;

static constexpr int B_ = 2, N_ = 4096, M_ = 512, K_ = 50;
static constexpr int BN = B_ * N_;   // 8192 points
static constexpr int BM = B_ * M_;   // 1024 grid points
static constexpr float EPS_ = 1e-5f;

DEV float lrelu(float z) { return z < 0.f ? 0.2f * z : z; }
DEV int clampi(int v, int hi) { return ((unsigned)v < (unsigned)hi) ? v : 0; }

// ---------------------------------------------------------------- dtype detect
// Classify input buffer: bf16 -> nearly all 16-bit words have exponent-field
// in [100,140]; f32 -> only ~55%. Writes flag: 1 = bf16, 0 = f32.
__global__ void k_detect(const unsigned short* __restrict__ xw, int* __restrict__ flag) {
    int t = threadIdx.x;
    int cnt = 0;
    for (int i = t; i < 4096; i += 256) {
        int e = (xw[i] >> 7) & 0xFF;
        if (e >= 100 && e <= 140) cnt++;
    }
    __shared__ int sh[256];
    sh[t] = cnt;
    __syncthreads();
    for (int s = 128; s; s >>= 1) { if (t < s) sh[t] += sh[t + s]; __syncthreads(); }
    if (t == 0) *flag = (sh[0] >= 3300) ? 1 : 0;
}

// ---------------------------------------------------------------- convert all params to f32
struct CvtDesc { const void* src; float* dst; int n; };
struct CvtArgs { CvtDesc d[25]; };
__global__ void k_convert(CvtArgs a, const int* __restrict__ flag) {
    CvtDesc dd = a.d[blockIdx.y];
    int i = blockIdx.x * 256 + threadIdx.x;
    if (i >= dd.n) return;
    float v = (*flag) ? __bfloat162float(((const bf16*)dd.src)[i])
                      : ((const float*)dd.src)[i];
    dd.dst[i] = v;
}

// ---------------------------------------------------------------- transpose (flag-branching reads)
DEV float rdval(const void* p, int i, int isbf) {
    return isbf ? __bfloat162float(((const bf16*)p)[i]) : ((const float*)p)[i];
}
__global__ void k_transpose(const void* __restrict__ x, const void* __restrict__ xg,
                            const int* __restrict__ flag,
                            float* __restrict__ xt, float* __restrict__ gt,
                            float* __restrict__ gT3) {
    int isbf = *flag;
    int i = blockIdx.x * 256 + threadIdx.x;
    if (i < BN) {
        int b = i / N_, n = i % N_;
        for (int c = 0; c < 3; c++) xt[i * 3 + c] = rdval(x, (b * 3 + c) * N_ + n, isbf);
    }
    if (i < BM) {
        int b = i / M_, m = i % M_;
        for (int c = 0; c < 3; c++) {
            float v = rdval(xg, (b * 3 + c) * M_ + m, isbf);
            gt[i * 3 + c] = v;
            gT3[(b * 3 + c) * M_ + m] = v;
        }
    }
}

// ---------------------------------------------------------------- row norms
template <int D>
__global__ void k_gnorm(const float* __restrict__ g, float* __restrict__ gn) {
    int i = blockIdx.x * 256 + threadIdx.x;
    if (i >= BM) return;
    float s = 0.f;
#pragma unroll
    for (int c = 0; c < D; c++) { float v = g[(size_t)i * D + c]; s = fmaf(v, v, s); }
    gn[i] = s;
}

// ---------------------------------------------------------------- (BM,64) -> (B,64,M)
__global__ void k_gt64(const float* __restrict__ g, float* __restrict__ gT) {
    int i = blockIdx.x * 256 + threadIdx.x;
    if (i >= BM * 64) return;
    int row = i >> 6, c = i & 63;
    int b = row / M_, m = row % M_;
    gT[((size_t)b * 64 + c) * M_ + m] = g[i];
}

// ---------------------------------------------------------------- nearest, D=3
__global__ void k_nearest3(const float* __restrict__ q, const float* __restrict__ gt,
                           const float* __restrict__ gn, int* __restrict__ nearest) {
    int i = blockIdx.x * 256 + threadIdx.x;
    if (i >= BN) return;
    int b = i / N_;
    float q0 = q[i * 3], q1 = q[i * 3 + 1], q2 = q[i * 3 + 2];
    float qn = q0 * q0 + q1 * q1 + q2 * q2;
    const float* gb = gt + (size_t)b * M_ * 3;
    const float* gnb = gn + b * M_;
    float best = 1e30f; int bi = 0;
    for (int m = 0; m < M_; m++) {
        float dot = q0 * gb[m * 3] + q1 * gb[m * 3 + 1] + q2 * gb[m * 3 + 2];
        float d = qn + gnb[m] - 2.f * dot;
        if (d < best) { best = d; bi = m; }
    }
    nearest[i] = bi;
}

// ---------------------------------------------------------------- nearest, D=64 (wave/point)
__global__ __launch_bounds__(256) void k_nearest64(const float* __restrict__ q,
                                                   const float* __restrict__ gT,
                                                   const float* __restrict__ gn,
                                                   int* __restrict__ nearest) {
    int lane = threadIdx.x & 63;
    int pt = blockIdx.x * 4 + (threadIdx.x >> 6);
    int b = pt / N_;
    const float* qrow = q + (size_t)pt * 64;
    float qs[64];
#pragma unroll
    for (int c = 0; c < 64; c++) qs[c] = qrow[c];
    float qn = 0.f;
#pragma unroll
    for (int c = 0; c < 64; c++) qn = fmaf(qs[c], qs[c], qn);
    const float* gTb = gT + (size_t)b * 64 * M_;
    const float* gnb = gn + b * M_;
    float best = 1e30f; int bi = 0;
    for (int j = 0; j < 8; j++) {
        int m = j * 64 + lane;
        float d0 = 0.f, d1 = 0.f;
#pragma unroll
        for (int c = 0; c < 64; c += 2) {
            d0 = fmaf(qs[c], gTb[c * M_ + m], d0);
            d1 = fmaf(qs[c + 1], gTb[(c + 1) * M_ + m], d1);
        }
        float d = qn + gnb[m] - 2.f * (d0 + d1);
        if (d < best) { best = d; bi = m; }
    }
    for (int off = 32; off; off >>= 1) {
        float ov = __shfl_xor(best, off);
        int oi = __shfl_xor(bi, off);
        if (ov < best || (ov == best && oi < bi)) { best = ov; bi = oi; }
    }
    if (lane == 0) nearest[pt] = clampi(bi, M_);
}

// ---------------------------------------------------------------- grid KNN (4 rows/block)
template <int D>
__global__ __launch_bounds__(256) void k_nbr(const float* __restrict__ g,
                                             const float* __restrict__ gT,
                                             const float* __restrict__ gn,
                                             int* __restrict__ nbr) {
    __shared__ float ds4[4][M_];
    int lane = threadIdx.x & 63, w = threadIdx.x >> 6;
    int row = blockIdx.x * 4 + w;
    int b = row / M_;
    const float* grow = g + (size_t)row * D;
    float qs[D];
#pragma unroll
    for (int c = 0; c < D; c++) qs[c] = grow[c];
    float qn = gn[row];
    const float* gTb = gT + (size_t)b * D * M_;
    const float* gnb = gn + b * M_;
    float* ds = ds4[w];
    for (int j = 0; j < 8; j++) {
        int m = j * 64 + lane;
        float dot = 0.f;
#pragma unroll
        for (int c = 0; c < D; c++) dot = fmaf(qs[c], gTb[c * M_ + m], dot);
        ds[m] = qn + gnb[m] - 2.f * dot;
    }
    __syncthreads();
    for (int it = 0; it < K_; it++) {
        float bv = 1e30f; int bi = 0x7fffffff;
        for (int j = 0; j < 8; j++) {
            int m = j * 64 + lane;
            float v = ds[m];
            if (v < bv || (v == bv && m < bi)) { bv = v; bi = m; }
        }
        for (int off = 32; off; off >>= 1) {
            float ov = __shfl_xor(bv, off);
            int oi = __shfl_xor(bi, off);
            if (ov < bv || (ov == bv && oi < bi)) { bv = ov; bi = oi; }
        }
        bi = clampi(bi, M_);   // NaN-safe: never emit sentinel
        if (lane == 0) { nbr[(size_t)row * K_ + it] = bi; ds[bi] = 1e30f; }
        __syncthreads();
    }
}

// ---------------------------------------------------------------- block stats -> slot-spread atomics
#define STATS_REDUCE_64(s1, s2, stats)                                            \
    {                                                                             \
        __shared__ float r1_[256], r2_[256];                                      \
        r1_[threadIdx.x] = (s1); r2_[threadIdx.x] = (s2);                         \
        __syncthreads();                                                          \
        if (threadIdx.x < 64) {                                                   \
            int t_ = threadIdx.x;                                                 \
            float a1_ = r1_[t_] + r1_[t_ + 64] + r1_[t_ + 128] + r1_[t_ + 192];   \
            float a2_ = r2_[t_] + r2_[t_ + 64] + r2_[t_ + 128] + r2_[t_ + 192];   \
            float* sp_ = (stats) + (blockIdx.x & 31) * 1024;                      \
            atomicAdd(&sp_[t_], a1_);                                             \
            atomicAdd(&sp_[64 + t_], a2_);                                        \
        }                                                                         \
    }

// ---------------------------------------------------------------- fused stage kernel
// MODE 0: stats(conv1); 1: bn1->lrelu->conv2, stats; 2: ...->bn2->lrelu->max;
// 3: bn1->lrelu->max (single-conv stage). All weights fp32 (pre-converted).
template <int D, int MODE>
__global__ __launch_bounds__(256) void k_stage(
    const float* __restrict__ q, const float* __restrict__ g,
    const int* __restrict__ nearest, const int* __restrict__ nbr,
    const float* __restrict__ W1, const float* __restrict__ W2,
    const float* __restrict__ prm1, const float* __restrict__ prm2,
    float* __restrict__ stats, float* __restrict__ xout) {
    int lane = threadIdx.x & 63;
    int pt = blockIdx.x * 4 + (threadIdx.x >> 6);
    int b = pt / N_;
    float Wa[D];
#pragma unroll
    for (int c = 0; c < D; c++) Wa[c] = W1[lane * 2 * D + c];
    float a1 = 0.f, sh1 = 0.f, a2 = 0.f, sh2 = 0.f;
    float W2r[(MODE == 1 || MODE == 2) ? 64 : 1];
    if constexpr (MODE >= 1) { a1 = prm1[lane]; sh1 = prm1[64 + lane]; }
    if constexpr (MODE == 1 || MODE == 2) {
#pragma unroll
        for (int c = 0; c < 64; c++) W2r[c] = W2[lane * 64 + c];
    }
    if constexpr (MODE == 2) { a2 = prm2[lane]; sh2 = prm2[64 + lane]; }
    int nr = clampi(nearest[pt], M_);
    const int* nrow = nbr + ((size_t)b * M_ + nr) * K_;
    float s1 = 0.f, s2 = 0.f, mx = -1e30f;
    float D0 = 0.f;
    float ctr_el = 0.f;
    float ctr3[(D <= 8) ? D : 1];
    if constexpr (D <= 8) {
        float Wd[D];
#pragma unroll
        for (int c = 0; c < D; c++) {
            ctr3[c] = q[(size_t)pt * D + c];
            Wd[c] = W1[lane * 2 * D + D + c] - Wa[c];
        }
#pragma unroll
        for (int c = 0; c < D; c++) D0 = fmaf(Wd[c], ctr3[c], D0);
    } else {
        ctr_el = q[(size_t)pt * 64 + lane];
#pragma unroll
        for (int c = 0; c < 64; c++) {
            float wb = W1[lane * 128 + 64 + c];
            D0 = fmaf(wb - Wa[c], __shfl(ctr_el, c), D0);
        }
    }
    for (int k = 0; k < K_; k++) {
        float y1;
        int idx = clampi(nrow[k], M_);
        if constexpr (D <= 8) {
            const float* gp = g + ((size_t)b * M_ + idx) * D;
            float acc = D0;
#pragma unroll
            for (int c = 0; c < D; c++) acc = fmaf(Wa[c], (k == 0 ? ctr3[c] : gp[c]), acc);
            y1 = acc;
        } else {
            float g_el = (k == 0) ? ctr_el : g[((size_t)b * M_ + idx) * 64 + lane];
            float acc = D0;
#pragma unroll
            for (int c = 0; c < 64; c++) acc = fmaf(Wa[c], __shfl(g_el, c), acc);
            y1 = acc;
        }
        if constexpr (MODE == 0) {
            s1 += y1; s2 = fmaf(y1, y1, s2);
        } else {
            float z = lrelu(fmaf(a1, y1, sh1));
            if constexpr (MODE == 3) {
                mx = fmaxf(mx, z);
            } else {
                float acc2 = 0.f;
#pragma unroll
                for (int c = 0; c < 64; c++) acc2 = fmaf(W2r[c], __shfl(z, c), acc2);
                if constexpr (MODE == 1) {
                    s1 += acc2; s2 = fmaf(acc2, acc2, s2);
                } else {
                    mx = fmaxf(mx, lrelu(fmaf(a2, acc2, sh2)));
                }
            }
        }
    }
    if constexpr (MODE == 0 || MODE == 1) {
        STATS_REDUCE_64(s1, s2, stats)
    } else {
        xout[(size_t)pt * 64 + lane] = mx;
    }
}

// ---------------------------------------------------------------- FPS gather
__global__ void k_gather(const float* __restrict__ xt, const int* __restrict__ FPS,
                         float* __restrict__ gt) {
    int row = blockIdx.x;
    int lane = threadIdx.x;
    int b = row / M_;
    int src = b * N_ + clampi(FPS[row], N_);
    gt[(size_t)row * 64 + lane] = xt[(size_t)src * 64 + lane];
}

// ---------------------------------------------------------------- BN finalize (f32 g/b)
__global__ void k_finalize(const float* __restrict__ stats, int O, int C,
                           const float* __restrict__ g, const float* __restrict__ bt,
                           float* __restrict__ prm) {
    int o = blockIdx.x * 256 + threadIdx.x;
    if (o >= O) return;
    double s1 = 0.0, s2 = 0.0;
    for (int s = 0; s < 32; s++) { s1 += stats[s * 1024 + o]; s2 += stats[s * 1024 + O + o]; }
    double m = s1 / C;
    double v = s2 / C - m * m;
    if (v < 0) v = 0;
    float sc = g[o] / sqrtf((float)v + EPS_);
    prm[o] = sc;
    prm[O + o] = bt[o] - (float)m * sc;
}

// ---------------------------------------------------------------- W6 conv (192->512)
__global__ __launch_bounds__(256) void k_conv_w6(
    const float* __restrict__ x1gt, const float* __restrict__ x2gt,
    const float* __restrict__ x3gt, const float* __restrict__ W6,
    float* __restrict__ y6, float* __restrict__ stats) {
    __shared__ float vl[8][192];
    int b = blockIdx.x / (M_ / 8);
    int m0 = (blockIdx.x % (M_ / 8)) * 8;
    for (int i = threadIdx.x; i < 8 * 192; i += 256) {
        int mi = i / 192, c = i % 192;
        const float* src = c < 64 ? x1gt : (c < 128 ? x2gt : x3gt);
        vl[mi][c] = src[((size_t)b * M_ + m0 + mi) * 64 + (c & 63)];
    }
    __syncthreads();
    float acc0[8] = {0}, acc1[8] = {0};
    int o0 = threadIdx.x, o1 = threadIdx.x + 256;
    for (int c = 0; c < 192; c++) {
        float w0 = W6[o0 * 192 + c];
        float w1 = W6[o1 * 192 + c];
#pragma unroll
        for (int m = 0; m < 8; m++) { float v = vl[m][c]; acc0[m] = fmaf(w0, v, acc0[m]); acc1[m] = fmaf(w1, v, acc1[m]); }
    }
    float s1a = 0, s2a = 0, s1b = 0, s2b = 0;
    for (int m = 0; m < 8; m++) {
        float ya = acc0[m], yb = acc1[m];
        y6[((size_t)b * M_ + m0 + m) * 512 + o0] = ya;
        y6[((size_t)b * M_ + m0 + m) * 512 + o1] = yb;
        s1a += ya; s2a = fmaf(ya, ya, s2a); s1b += yb; s2b = fmaf(yb, yb, s2b);
    }
    float* sp = stats + (blockIdx.x & 31) * 1024;
    atomicAdd(&sp[o0], s1a); atomicAdd(&sp[512 + o0], s2a);
    atomicAdd(&sp[o1], s1b); atomicAdd(&sp[512 + o1], s2b);
}

// ---------------------------------------------------------------- bn6+lrelu+max over M
__global__ void k_maxM(const float* __restrict__ y6, const float* __restrict__ prm,
                       float* __restrict__ xgmax) {
    int t = blockIdx.x * blockDim.x + threadIdx.x;
    if (t >= B_ * 512) return;
    int b = t / 512, o = t % 512;
    float a = prm[o], sh = prm[512 + o];
    float mx = -1e30f;
    for (int m = 0; m < M_; m++) {
        float z = lrelu(fmaf(a, y6[((size_t)b * M_ + m) * 512 + o], sh));
        mx = fmaxf(mx, z);
    }
    xgmax[t] = mx;
}

// ---------------------------------------------------------------- P7 = W7[:, :512] . xgmax
__global__ void k_p7(const float* __restrict__ xgmax, const float* __restrict__ W7,
                     float* __restrict__ p7) {
    int t = blockIdx.x * blockDim.x + threadIdx.x;
    if (t >= B_ * 128) return;
    int b = t / 128, o = t % 128;
    float acc = 0.f;
    for (int c = 0; c < 512; c++) acc = fmaf(W7[o * 704 + c], xgmax[b * 512 + c], acc);
    p7[t] = acc;
}

// ---------------------------------------------------------------- W7 conv (704->128), 192 variable
__global__ __launch_bounds__(256) void k_conv_w7(
    const float* __restrict__ x1t, const float* __restrict__ x2t,
    const float* __restrict__ x3t, const float* __restrict__ p7,
    const float* __restrict__ W7, float* __restrict__ y7, float* __restrict__ stats) {
    __shared__ float vl[16][192];
    int item0 = blockIdx.x * 16;
    for (int i = threadIdx.x; i < 16 * 192; i += 256) {
        int it = i / 192, c = i % 192;
        const float* src = c < 64 ? x1t : (c < 128 ? x2t : x3t);
        vl[it][c] = src[((size_t)(item0 + it)) * 64 + (c & 63)];
    }
    __syncthreads();
    int o = threadIdx.x & 127, h = threadIdx.x >> 7;
    float acc[8] = {0};
    for (int c = 0; c < 192; c++) {
        float w = W7[o * 704 + 512 + c];
#pragma unroll
        for (int i = 0; i < 8; i++) acc[i] = fmaf(w, vl[h * 8 + i][c], acc[i]);
    }
    float s1 = 0, s2 = 0;
    for (int i = 0; i < 8; i++) {
        int item = item0 + h * 8 + i;
        int b = item / N_;
        float yv = p7[b * 128 + o] + acc[i];
        y7[(size_t)item * 128 + o] = yv;
        s1 += yv; s2 = fmaf(yv, yv, s2);
    }
    __shared__ float r1[256], r2[256];
    r1[threadIdx.x] = s1; r2[threadIdx.x] = s2;
    __syncthreads();
    if (threadIdx.x < 128) {
        float* sp = stats + (blockIdx.x & 31) * 1024;
        atomicAdd(&sp[threadIdx.x], r1[threadIdx.x] + r1[threadIdx.x + 128]);
        atomicAdd(&sp[128 + threadIdx.x], r2[threadIdx.x] + r2[threadIdx.x + 128]);
    }
}

// ---------------------------------------------------------------- W8 conv (128->64)
__global__ __launch_bounds__(256) void k_conv_w8(
    const float* __restrict__ y7, const float* __restrict__ prm7,
    const float* __restrict__ W8, float* __restrict__ y8, float* __restrict__ stats) {
    int lane = threadIdx.x & 63;
    int item = blockIdx.x * 4 + (threadIdx.x >> 6);
    float W0[64], W1r[64];
#pragma unroll
    for (int c = 0; c < 64; c++) {
        W0[c] = W8[lane * 128 + c];
        W1r[c] = W8[lane * 128 + 64 + c];
    }
    float a0 = prm7[lane], sh0 = prm7[128 + lane];
    float a1 = prm7[64 + lane], sh1 = prm7[128 + 64 + lane];
    float z0 = lrelu(fmaf(a0, y7[(size_t)item * 128 + lane], sh0));
    float z1 = lrelu(fmaf(a1, y7[(size_t)item * 128 + 64 + lane], sh1));
    float acc = 0.f;
#pragma unroll
    for (int c = 0; c < 64; c++) {
        acc = fmaf(W0[c], __shfl(z0, c), acc);
        acc = fmaf(W1r[c], __shfl(z1, c), acc);
    }
    y8[(size_t)item * 64 + lane] = acc;
    STATS_REDUCE_64(acc, acc * acc, stats)
}

// ---------------------------------------------------------------- final: bn8+lrelu, W9 -> out
__global__ __launch_bounds__(256) void k_final(
    const float* __restrict__ y8, const float* __restrict__ prm8,
    const float* __restrict__ W9, void* __restrict__ out, const int* __restrict__ flag) {
    __shared__ float zl[2][64];
    int item0 = blockIdx.x * 2;
    if (threadIdx.x < 128) {
        int it = threadIdx.x >> 6, c = threadIdx.x & 63;
        float z = fmaf(prm8[c], y8[(size_t)(item0 + it) * 64 + c], prm8[64 + c]);
        zl[it][c] = lrelu(z);
    }
    __syncthreads();
    int it = threadIdx.x >> 7, o = threadIdx.x & 127;
    float acc = 0.f;
#pragma unroll
    for (int c = 0; c < 64; c++) acc = fmaf(W9[o * 64 + c], zl[it][c], acc);
    size_t oi = (size_t)(item0 + it) * 128 + o;
    if (*flag) ((bf16*)out)[oi] = __float2bfloat16(acc);
    else ((float*)out)[oi] = acc;
}

// ---------------------------------------------------------------- host
extern "C" void kernel_launch(void* const* d_in, const int* in_sizes, int n_in,
                              void* d_out, int out_size, void* d_ws, size_t ws_size,
                              hipStream_t stream) {
    (void)in_sizes; (void)n_in; (void)out_size; (void)ws_size;
    const void* x = d_in[0];
    const void* xgrid = d_in[1];
    const int* FPS = (const int*)d_in[2];

    char* ws = (char*)d_ws;
    size_t off = 0;
    auto alloc = [&](size_t bytes) -> char* {
        char* p = ws + off;
        off = (off + bytes + 255) & ~(size_t)255;
        return p;
    };
    int* flag    = (int*)alloc(256);
    float* stats = (float*)alloc(8 * 32 * 1024 * sizeof(float));   // 1 MB
    float* prm   = (float*)alloc(8 * 1024 * sizeof(float));
    // converted fp32 params
    static const int wsz[9] = {384, 4096, 8192, 4096, 8192, 98304, 90112, 8192, 8192};
    static const int dims[8] = {64, 64, 64, 64, 64, 512, 128, 64};
    float* cW[9];
    for (int i = 0; i < 9; i++) cW[i] = (float*)alloc((size_t)wsz[i] * 4);
    float* cG[8];
    float* cB[8];
    for (int j = 0; j < 8; j++) {
        cG[j] = (float*)alloc((size_t)dims[j] * 4);
        cB[j] = (float*)alloc((size_t)dims[j] * 4);
    }
    float* xt    = (float*)alloc((size_t)BN * 3 * 4);
    float* gt    = (float*)alloc((size_t)BM * 3 * 4);
    float* gT3   = (float*)alloc((size_t)B_ * 3 * M_ * 4);
    float* gn    = (float*)alloc((size_t)BM * 4);
    int* nearest = (int*)alloc((size_t)BN * 4);
    int* nbr     = (int*)alloc((size_t)BM * K_ * 4);
    float* x1t   = (float*)alloc((size_t)BN * 64 * 4);
    float* x2t   = (float*)alloc((size_t)BN * 64 * 4);
    float* x3t   = (float*)alloc((size_t)BN * 64 * 4);
    float* x1gt  = (float*)alloc((size_t)BM * 64 * 4);
    float* x2gt  = (float*)alloc((size_t)BM * 64 * 4);
    float* x3gt  = (float*)alloc((size_t)BM * 64 * 4);
    float* gT64  = (float*)alloc((size_t)B_ * 64 * M_ * 4);
    float* y6    = (float*)alloc((size_t)BM * 512 * 4);
    float* xgmax = (float*)alloc((size_t)B_ * 512 * 4);
    float* p7    = (float*)alloc((size_t)B_ * 128 * 4);
    float* y7    = (float*)alloc((size_t)BN * 128 * 4);
    float* y8    = (float*)alloc((size_t)BN * 64 * 4);
    // total ~18.3 MB

    hipMemsetAsync(stats, 0, 8 * 32 * 1024 * sizeof(float), stream);
    k_detect<<<1, 256, 0, stream>>>((const unsigned short*)x, flag);

    CvtArgs ca;
    for (int i = 0; i < 9; i++) ca.d[i] = {d_in[3 + i], cW[i], wsz[i]};
    for (int j = 0; j < 8; j++) {
        ca.d[9 + 2 * j]     = {d_in[12 + 2 * j], cG[j], dims[j]};
        ca.d[9 + 2 * j + 1] = {d_in[13 + 2 * j], cB[j], dims[j]};
    }
    k_convert<<<dim3(384, 25), 256, 0, stream>>>(ca, flag);
    k_transpose<<<(BN + 255) / 256, 256, 0, stream>>>(x, xgrid, flag, xt, gt, gT3);

    const int SG = BN / 4;     // k_stage grid (wave per point)
    const int CK = BN * K_;    // edge-conv BN stat count

    // ---- stage A (D=3, W1,W2) ----
    k_gnorm<3><<<4, 256, 0, stream>>>(gt, gn);
    k_nearest3<<<(BN + 255) / 256, 256, 0, stream>>>(xt, gt, gn, nearest);
    k_nbr<3><<<BM / 4, 256, 0, stream>>>(gt, gT3, gn, nbr);
    k_stage<3, 0><<<SG, 256, 0, stream>>>(xt, gt, nearest, nbr, cW[0], nullptr, nullptr, nullptr, stats + 0 * 32768, nullptr);
    k_finalize<<<2, 256, 0, stream>>>(stats + 0 * 32768, 64, CK, cG[0], cB[0], prm + 0 * 1024);
    k_stage<3, 1><<<SG, 256, 0, stream>>>(xt, gt, nearest, nbr, cW[0], cW[1], prm + 0 * 1024, nullptr, stats + 1 * 32768, nullptr);
    k_finalize<<<2, 256, 0, stream>>>(stats + 1 * 32768, 64, CK, cG[1], cB[1], prm + 1 * 1024);
    k_stage<3, 2><<<SG, 256, 0, stream>>>(xt, gt, nearest, nbr, cW[0], cW[1], prm + 0 * 1024, prm + 1 * 1024, nullptr, x1t);
    k_gather<<<BM, 64, 0, stream>>>(x1t, FPS, x1gt);

    // ---- stage B (D=64, W3,W4) ----
    k_gt64<<<BM * 64 / 256, 256, 0, stream>>>(x1gt, gT64);
    k_gnorm<64><<<4, 256, 0, stream>>>(x1gt, gn);
    k_nearest64<<<SG, 256, 0, stream>>>(x1t, gT64, gn, nearest);
    k_nbr<64><<<BM / 4, 256, 0, stream>>>(x1gt, gT64, gn, nbr);
    k_stage<64, 0><<<SG, 256, 0, stream>>>(x1t, x1gt, nearest, nbr, cW[2], nullptr, nullptr, nullptr, stats + 2 * 32768, nullptr);
    k_finalize<<<2, 256, 0, stream>>>(stats + 2 * 32768, 64, CK, cG[2], cB[2], prm + 2 * 1024);
    k_stage<64, 1><<<SG, 256, 0, stream>>>(x1t, x1gt, nearest, nbr, cW[2], cW[3], prm + 2 * 1024, nullptr, stats + 3 * 32768, nullptr);
    k_finalize<<<2, 256, 0, stream>>>(stats + 3 * 32768, 64, CK, cG[3], cB[3], prm + 3 * 1024);
    k_stage<64, 2><<<SG, 256, 0, stream>>>(x1t, x1gt, nearest, nbr, cW[2], cW[3], prm + 2 * 1024, prm + 3 * 1024, nullptr, x2t);
    k_gather<<<BM, 64, 0, stream>>>(x2t, FPS, x2gt);

    // ---- stage C (D=64, W5 single conv) ----
    k_gt64<<<BM * 64 / 256, 256, 0, stream>>>(x2gt, gT64);
    k_gnorm<64><<<4, 256, 0, stream>>>(x2gt, gn);
    k_nearest64<<<SG, 256, 0, stream>>>(x2t, gT64, gn, nearest);
    k_nbr<64><<<BM / 4, 256, 0, stream>>>(x2gt, gT64, gn, nbr);
    k_stage<64, 0><<<SG, 256, 0, stream>>>(x2t, x2gt, nearest, nbr, cW[4], nullptr, nullptr, nullptr, stats + 4 * 32768, nullptr);
    k_finalize<<<2, 256, 0, stream>>>(stats + 4 * 32768, 64, CK, cG[4], cB[4], prm + 4 * 1024);
    k_stage<64, 3><<<SG, 256, 0, stream>>>(x2t, x2gt, nearest, nbr, cW[4], nullptr, prm + 4 * 1024, nullptr, nullptr, x3t);
    k_gather<<<BM, 64, 0, stream>>>(x3t, FPS, x3gt);

    // ---- global MLP tail ----
    k_conv_w6<<<BM / 8, 256, 0, stream>>>(x1gt, x2gt, x3gt, cW[5], y6, stats + 5 * 32768);
    k_finalize<<<2, 256, 0, stream>>>(stats + 5 * 32768, 512, BM, cG[5], cB[5], prm + 5 * 1024);
    k_maxM<<<(B_ * 512 + 255) / 256, 256, 0, stream>>>(y6, prm + 5 * 1024, xgmax);
    k_p7<<<1, 256, 0, stream>>>(xgmax, cW[6], p7);
    k_conv_w7<<<BN / 16, 256, 0, stream>>>(x1t, x2t, x3t, p7, cW[6], y7, stats + 6 * 32768);
    k_finalize<<<2, 256, 0, stream>>>(stats + 6 * 32768, 128, BN, cG[6], cB[6], prm + 6 * 1024);
    k_conv_w8<<<BN / 4, 256, 0, stream>>>(y7, prm + 6 * 1024, cW[7], y8, stats + 7 * 32768);
    k_finalize<<<2, 256, 0, stream>>>(stats + 7 * 32768, 64, BN, cG[7], cB[7], prm + 7 * 1024);
    k_final<<<BN / 2, 256, 0, stream>>>(y8, prm + 7 * 1024, cW[8], d_out, flag);
}

// Round 4
// 982.649 us; speedup vs baseline: 3.5897x; 3.5897x over previous
//
#include <hip/hip_runtime.h>
#include <hip/hip_bf16.h>

#define DEV __device__ __forceinline__
using bf16 = __hip_bfloat16;

static constexpr int B_ = 2, N_ = 4096, M_ = 512, K_ = 50;
static constexpr int BN = B_ * N_;   // 8192 points
static constexpr int BM = B_ * M_;   // 1024 grid points
static constexpr float EPS_ = 1e-5f;

DEV float lrelu(float z) { return z < 0.f ? 0.2f * z : z; }
DEV int clampi(int v, int hi) { return ((unsigned)v < (unsigned)hi) ? v : 0; }

// ---------------------------------------------------------------- dtype detect
__global__ void k_detect(const unsigned short* __restrict__ xw, int* __restrict__ flag) {
    int t = threadIdx.x;
    int cnt = 0;
    for (int i = t; i < 4096; i += 256) {
        int e = (xw[i] >> 7) & 0xFF;
        if (e >= 100 && e <= 140) cnt++;
    }
    __shared__ int sh[256];
    sh[t] = cnt;
    __syncthreads();
    for (int s = 128; s; s >>= 1) { if (t < s) sh[t] += sh[t + s]; __syncthreads(); }
    if (t == 0) *flag = (sh[0] >= 3300) ? 1 : 0;
}

// ---------------------------------------------------------------- convert params to f32
struct CvtDesc { const void* src; float* dst; int n; };
struct CvtArgs { CvtDesc d[25]; };
__global__ void k_convert(CvtArgs a, const int* __restrict__ flag) {
    CvtDesc dd = a.d[blockIdx.y];
    int i = blockIdx.x * 256 + threadIdx.x;
    if (i >= dd.n) return;
    float v = (*flag) ? __bfloat162float(((const bf16*)dd.src)[i])
                      : ((const float*)dd.src)[i];
    dd.dst[i] = v;
}

// ---------------------------------------------------------------- transpose
DEV float rdval(const void* p, int i, int isbf) {
    return isbf ? __bfloat162float(((const bf16*)p)[i]) : ((const float*)p)[i];
}
__global__ void k_transpose(const void* __restrict__ x, const void* __restrict__ xg,
                            const int* __restrict__ flag,
                            float* __restrict__ xt, float* __restrict__ gt,
                            float* __restrict__ gT3) {
    int isbf = *flag;
    int i = blockIdx.x * 256 + threadIdx.x;
    if (i < BN) {
        int b = i / N_, n = i % N_;
        for (int c = 0; c < 3; c++) xt[i * 3 + c] = rdval(x, (b * 3 + c) * N_ + n, isbf);
    }
    if (i < BM) {
        int b = i / M_, m = i % M_;
        for (int c = 0; c < 3; c++) {
            float v = rdval(xg, (b * 3 + c) * M_ + m, isbf);
            gt[i * 3 + c] = v;
            gT3[(b * 3 + c) * M_ + m] = v;
        }
    }
}

// ---------------------------------------------------------------- row norms
template <int D>
__global__ void k_gnorm(const float* __restrict__ g, float* __restrict__ gn) {
    int i = blockIdx.x * 256 + threadIdx.x;
    if (i >= BM) return;
    float s = 0.f;
#pragma unroll
    for (int c = 0; c < D; c++) { float v = g[(size_t)i * D + c]; s = fmaf(v, v, s); }
    gn[i] = s;
}

// ---------------------------------------------------------------- (BM,64) -> (B,64,M)
__global__ void k_gt64(const float* __restrict__ g, float* __restrict__ gT) {
    int i = blockIdx.x * 256 + threadIdx.x;
    if (i >= BM * 64) return;
    int row = i >> 6, c = i & 63;
    int b = row / M_, m = row % M_;
    gT[((size_t)b * 64 + c) * M_ + m] = g[i];
}

// ---------------------------------------------------------------- nearest, D=3
__global__ void k_nearest3(const float* __restrict__ q, const float* __restrict__ gt,
                           const float* __restrict__ gn, int* __restrict__ nearest) {
    int i = blockIdx.x * 256 + threadIdx.x;
    if (i >= BN) return;
    int b = i / N_;
    float q0 = q[i * 3], q1 = q[i * 3 + 1], q2 = q[i * 3 + 2];
    float qn = q0 * q0 + q1 * q1 + q2 * q2;
    const float* gb = gt + (size_t)b * M_ * 3;
    const float* gnb = gn + b * M_;
    float best = 1e30f; int bi = 0;
    for (int m = 0; m < M_; m++) {
        float dot = q0 * gb[m * 3] + q1 * gb[m * 3 + 1] + q2 * gb[m * 3 + 2];
        float d = qn + gnb[m] - 2.f * dot;
        if (d < best) { best = d; bi = m; }
    }
    nearest[i] = bi;
}

// ---------------------------------------------------------------- nearest, D=64 (wave/point)
__global__ __launch_bounds__(256) void k_nearest64(const float* __restrict__ q,
                                                   const float* __restrict__ gT,
                                                   const float* __restrict__ gn,
                                                   int* __restrict__ nearest) {
    int lane = threadIdx.x & 63;
    int pt = blockIdx.x * 4 + __builtin_amdgcn_readfirstlane(threadIdx.x >> 6);
    int b = pt >> 12;
    const float* qrow = q + (size_t)pt * 64;
    float qs[64];
#pragma unroll
    for (int c = 0; c < 64; c++) qs[c] = qrow[c];
    float qn = 0.f;
#pragma unroll
    for (int c = 0; c < 64; c++) qn = fmaf(qs[c], qs[c], qn);
    const float* gTb = gT + (size_t)b * 64 * M_;
    const float* gnb = gn + b * M_;
    float best = 1e30f; int bi = 0;
    for (int j = 0; j < 8; j++) {
        int m = j * 64 + lane;
        float d0 = 0.f, d1 = 0.f;
#pragma unroll
        for (int c = 0; c < 64; c += 2) {
            d0 = fmaf(qs[c], gTb[c * M_ + m], d0);
            d1 = fmaf(qs[c + 1], gTb[(c + 1) * M_ + m], d1);
        }
        float d = qn + gnb[m] - 2.f * (d0 + d1);
        if (d < best) { best = d; bi = m; }
    }
    for (int off = 32; off; off >>= 1) {
        float ov = __shfl_xor(best, off);
        int oi = __shfl_xor(bi, off);
        if (ov < best || (ov == best && oi < bi)) { best = ov; bi = oi; }
    }
    if (lane == 0) nearest[pt] = clampi(bi, M_);
}

// ---------------------------------------------------------------- grid KNN (4 rows/block)
template <int D>
__global__ __launch_bounds__(256) void k_nbr(const float* __restrict__ g,
                                             const float* __restrict__ gT,
                                             const float* __restrict__ gn,
                                             int* __restrict__ nbr) {
    __shared__ float ds4[4][M_];
    int lane = threadIdx.x & 63, w = threadIdx.x >> 6;
    int row = blockIdx.x * 4 + w;
    int b = row / M_;
    const float* grow = g + (size_t)row * D;
    float qs[D];
#pragma unroll
    for (int c = 0; c < D; c++) qs[c] = grow[c];
    float qn = gn[row];
    const float* gTb = gT + (size_t)b * D * M_;
    const float* gnb = gn + b * M_;
    float* ds = ds4[w];
    for (int j = 0; j < 8; j++) {
        int m = j * 64 + lane;
        float dot = 0.f;
#pragma unroll
        for (int c = 0; c < D; c++) dot = fmaf(qs[c], gTb[c * M_ + m], dot);
        ds[m] = qn + gnb[m] - 2.f * dot;
    }
    __syncthreads();
    for (int it = 0; it < K_; it++) {
        float bv = 1e30f; int bi = 0x7fffffff;
        for (int j = 0; j < 8; j++) {
            int m = j * 64 + lane;
            float v = ds[m];
            if (v < bv || (v == bv && m < bi)) { bv = v; bi = m; }
        }
        for (int off = 32; off; off >>= 1) {
            float ov = __shfl_xor(bv, off);
            int oi = __shfl_xor(bi, off);
            if (ov < bv || (ov == bv && oi < bi)) { bv = ov; bi = oi; }
        }
        bi = clampi(bi, M_);
        if (lane == 0) { nbr[(size_t)row * K_ + it] = bi; ds[bi] = 1e30f; }
        __syncthreads();
    }
}

// ---------------------------------------------------------------- block stats (lane = channel)
#define STATS_REDUCE_64(s1, s2, stats)                                            \
    {                                                                             \
        __shared__ float r1_[256], r2_[256];                                      \
        r1_[threadIdx.x] = (s1); r2_[threadIdx.x] = (s2);                         \
        __syncthreads();                                                          \
        if (threadIdx.x < 64) {                                                   \
            int t_ = threadIdx.x;                                                 \
            float a1_ = r1_[t_] + r1_[t_ + 64] + r1_[t_ + 128] + r1_[t_ + 192];   \
            float a2_ = r2_[t_] + r2_[t_ + 64] + r2_[t_ + 128] + r2_[t_ + 192];   \
            float* sp_ = (stats) + (blockIdx.x & 31) * 1024;                      \
            atomicAdd(&sp_[t_], a1_);                                             \
            atomicAdd(&sp_[64 + t_], a2_);                                        \
        }                                                                         \
    }

// ---------------------------------------------------------------- Pg[m][o] = sum_c Wa[o][c]*g[m][c]
template <int D>
__global__ __launch_bounds__(256) void k_pgrid(const float* __restrict__ g,
                                               const float* __restrict__ W1,
                                               float* __restrict__ Pg) {
    int lane = threadIdx.x & 63;
    int row = blockIdx.x * 4 + __builtin_amdgcn_readfirstlane(threadIdx.x >> 6);
    float acc;
    if constexpr (D == 3) {
        float c0 = g[row * 3], c1 = g[row * 3 + 1], c2 = g[row * 3 + 2];
        const float* wr = W1 + lane * 6;
        acc = fmaf(wr[0], c0, fmaf(wr[1], c1, wr[2] * c2));
    } else {
        float ge = g[(size_t)row * 64 + lane];
        const float* wr = W1 + lane * 128;
        acc = 0.f;
#pragma unroll
        for (int c = 0; c < 64; c++) acc = fmaf(wr[c], __shfl(ge, c), acc);
    }
    Pg[(size_t)row * 64 + lane] = acc;
}

// ---------------------------------------------------------------- per-point D0 = (Wb-Wa).ctr, S0 = Wb.ctr
template <int D>
__global__ __launch_bounds__(256) void k_prep(const float* __restrict__ q,
                                              const float* __restrict__ W1,
                                              float* __restrict__ D0,
                                              float* __restrict__ S0) {
    int lane = threadIdx.x & 63;
    int pt = blockIdx.x * 4 + __builtin_amdgcn_readfirstlane(threadIdx.x >> 6);
    float pa, pb;
    if constexpr (D == 3) {
        float c0 = q[pt * 3], c1 = q[pt * 3 + 1], c2 = q[pt * 3 + 2];
        const float* wr = W1 + lane * 6;
        pa = fmaf(wr[0], c0, fmaf(wr[1], c1, wr[2] * c2));
        pb = fmaf(wr[3], c0, fmaf(wr[4], c1, wr[5] * c2));
    } else {
        float ge = q[(size_t)pt * 64 + lane];
        const float* wr = W1 + lane * 128;
        pa = 0.f; pb = 0.f;
#pragma unroll
        for (int c = 0; c < 64; c++) {
            float sh = __shfl(ge, c);
            pa = fmaf(wr[c], sh, pa);
            pb = fmaf(wr[64 + c], sh, pb);
        }
    }
    D0[(size_t)pt * 64 + lane] = pb - pa;
    S0[(size_t)pt * 64 + lane] = pb;   // y1 at k=0 (feat==ctr): Wb.ctr
}

// ---------------------------------------------------------------- pass0: stats of y1 (+min/max for single-conv stage)
template <int MINMAX>
__global__ __launch_bounds__(256) void k_pass0(
    const float* __restrict__ Pg, const float* __restrict__ D0,
    const float* __restrict__ S0, const int* __restrict__ nearest,
    const int* __restrict__ nbr, float* __restrict__ stats,
    float* __restrict__ mn_out, float* __restrict__ mx_out) {
    int lane = threadIdx.x & 63;
    int pt = blockIdx.x * 4 + __builtin_amdgcn_readfirstlane(threadIdx.x >> 6);
    int b = pt >> 12;
    int nr = clampi(nearest[pt], M_);
    const int* nrow = nbr + ((size_t)b * M_ + nr) * K_;
    int idxv = (lane < K_) ? clampi(nrow[lane], M_) : 0;   // idx in lane k
    float d0 = D0[(size_t)pt * 64 + lane];
    float v0 = S0[(size_t)pt * 64 + lane];
    float s1 = v0, s2 = v0 * v0, mn = v0, mx = v0;
    const float* Pgb = Pg + (size_t)b * M_ * 64;
#pragma unroll 7
    for (int k = 1; k < K_; k++) {
        int idx = __shfl(idxv, k);
        float v = d0 + Pgb[(size_t)idx * 64 + lane];
        s1 += v; s2 = fmaf(v, v, s2);
        if (MINMAX) { mn = fminf(mn, v); mx = fmaxf(mx, v); }
    }
    if (MINMAX) {
        mn_out[(size_t)pt * 64 + lane] = mn;
        mx_out[(size_t)pt * 64 + lane] = mx;
    }
    STATS_REDUCE_64(s1, s2, stats)
}

// ---------------------------------------------------------------- pass1: bn1+lrelu -> conv2 -> stats + min/max of y2
// lane = k. Weights via wave-uniform float4 loads (SMEM-scalarizable).
__global__ __launch_bounds__(256) void k_pass1(
    const float* __restrict__ Pg, const float* __restrict__ D0,
    const float* __restrict__ S0, const int* __restrict__ nearest,
    const int* __restrict__ nbr, const float* __restrict__ prm1,
    const float* __restrict__ W2, float* __restrict__ stats,
    float* __restrict__ mn_out, float* __restrict__ mx_out) {
    __shared__ float tile[4][64 * 17];
    int lane = threadIdx.x & 63;
    int wv = __builtin_amdgcn_readfirstlane(threadIdx.x >> 6);
    int pt = blockIdx.x * 4 + wv;
    int b = pt >> 12;
    int nr = clampi(nearest[pt], M_);
    const int* nrow = nbr + ((size_t)b * M_ + nr) * K_;
    int k = lane;
    int idx = (k >= 1 && k < K_) ? clampi(nrow[k], M_) : 0;
    const float4* src = (k == 0) ? (const float4*)(S0 + (size_t)pt * 64)
                                 : (const float4*)(Pg + ((size_t)b * M_ + idx) * 64);
    const float4* d0r = (const float4*)(D0 + (size_t)pt * 64);
    const float4* a4 = (const float4*)(prm1);
    const float4* s4 = (const float4*)(prm1 + 64);
    float dscale = (k == 0) ? 0.f : 1.f;
    float z[64];
#pragma unroll
    for (int c4 = 0; c4 < 16; c4++) {
        float4 v = src[c4]; float4 d = d0r[c4]; float4 a = a4[c4]; float4 s = s4[c4];
        z[4 * c4 + 0] = lrelu(fmaf(a.x, fmaf(dscale, d.x, v.x), s.x));
        z[4 * c4 + 1] = lrelu(fmaf(a.y, fmaf(dscale, d.y, v.y), s.y));
        z[4 * c4 + 2] = lrelu(fmaf(a.z, fmaf(dscale, d.z, v.z), s.z));
        z[4 * c4 + 3] = lrelu(fmaf(a.w, fmaf(dscale, d.w, v.w), s.w));
    }
    float* tl = tile[wv];
    int o_l = lane & 15, kg = lane >> 4;
    float s1a[4], s2a[4], mna[4], mxa[4];
#pragma unroll
    for (int ch = 0; ch < 4; ch++) {
        for (int ol = 0; ol < 16; ol++) {
            int o = ch * 16 + ol;
            const float4* wr = (const float4*)(W2 + o * 64);
            float acc = 0.f;
#pragma unroll
            for (int c4 = 0; c4 < 16; c4++) {
                float4 w = wr[c4];
                acc = fmaf(w.x, z[4 * c4 + 0], acc);
                acc = fmaf(w.y, z[4 * c4 + 1], acc);
                acc = fmaf(w.z, z[4 * c4 + 2], acc);
                acc = fmaf(w.w, z[4 * c4 + 3], acc);
            }
            tl[lane * 17 + ol] = acc;   // bank (17k+ol)%32: conflict-free (2-way max)
        }
        // redistribute: lane -> (o_l, k-group); DS ops in a wave complete in order.
        float p1 = 0.f, p2 = 0.f, pm = -1e30f, pn = 1e30f;
#pragma unroll
        for (int i = 0; i < 16; i++) {
            int kk = kg * 16 + i;
            if (kk < K_) {
                float v = tl[kk * 17 + o_l];
                p1 += v; p2 = fmaf(v, v, p2);
                pm = fmaxf(pm, v); pn = fminf(pn, v);
            }
        }
        p1 += __shfl_xor(p1, 16); p1 += __shfl_xor(p1, 32);
        p2 += __shfl_xor(p2, 16); p2 += __shfl_xor(p2, 32);
        pm = fmaxf(pm, __shfl_xor(pm, 16)); pm = fmaxf(pm, __shfl_xor(pm, 32));
        pn = fminf(pn, __shfl_xor(pn, 16)); pn = fminf(pn, __shfl_xor(pn, 32));
        s1a[ch] = p1; s2a[ch] = p2; mxa[ch] = pm; mna[ch] = pn;
    }
    if (lane < 16) {
        float* sp = stats + (blockIdx.x & 31) * 1024;
#pragma unroll
        for (int ch = 0; ch < 4; ch++) {
            int o = ch * 16 + lane;
            mn_out[(size_t)pt * 64 + o] = mna[ch];
            mx_out[(size_t)pt * 64 + o] = mxa[ch];
            atomicAdd(&sp[o], s1a[ch]);
            atomicAdd(&sp[64 + o], s2a[ch]);
        }
    }
}

// ---------------------------------------------------------------- apply bn+lrelu to min/max (exact via monotonicity)
__global__ void k_apply(const float* __restrict__ mn, const float* __restrict__ mx,
                        const float* __restrict__ prm, float* __restrict__ xout) {
    int t = blockIdx.x * 256 + threadIdx.x;   // BN*64
    int o = t & 63;
    float a = prm[o], sh = prm[64 + o];
    float v = a > 0.f ? mx[t] : mn[t];
    xout[t] = lrelu(fmaf(a, v, sh));
}

// ---------------------------------------------------------------- FPS gather
__global__ void k_gather(const float* __restrict__ xt, const int* __restrict__ FPS,
                         float* __restrict__ gt) {
    int row = blockIdx.x;
    int lane = threadIdx.x;
    int b = row / M_;
    int src = b * N_ + clampi(FPS[row], N_);
    gt[(size_t)row * 64 + lane] = xt[(size_t)src * 64 + lane];
}

// ---------------------------------------------------------------- BN finalize
__global__ void k_finalize(const float* __restrict__ stats, int O, int C,
                           const float* __restrict__ g, const float* __restrict__ bt,
                           float* __restrict__ prm) {
    int o = blockIdx.x * 256 + threadIdx.x;
    if (o >= O) return;
    double s1 = 0.0, s2 = 0.0;
    for (int s = 0; s < 32; s++) { s1 += stats[s * 1024 + o]; s2 += stats[s * 1024 + O + o]; }
    double m = s1 / C;
    double v = s2 / C - m * m;
    if (v < 0) v = 0;
    float sc = g[o] / sqrtf((float)v + EPS_);
    prm[o] = sc;
    prm[O + o] = bt[o] - (float)m * sc;
}

// ---------------------------------------------------------------- W6 conv (192->512)
__global__ __launch_bounds__(256) void k_conv_w6(
    const float* __restrict__ x1gt, const float* __restrict__ x2gt,
    const float* __restrict__ x3gt, const float* __restrict__ W6,
    float* __restrict__ y6, float* __restrict__ stats) {
    __shared__ float vl[8][192];
    int b = blockIdx.x / (M_ / 8);
    int m0 = (blockIdx.x % (M_ / 8)) * 8;
    for (int i = threadIdx.x; i < 8 * 192; i += 256) {
        int mi = i / 192, c = i % 192;
        const float* src = c < 64 ? x1gt : (c < 128 ? x2gt : x3gt);
        vl[mi][c] = src[((size_t)b * M_ + m0 + mi) * 64 + (c & 63)];
    }
    __syncthreads();
    float acc0[8] = {0}, acc1[8] = {0};
    int o0 = threadIdx.x, o1 = threadIdx.x + 256;
    for (int c = 0; c < 192; c++) {
        float w0 = W6[o0 * 192 + c];
        float w1 = W6[o1 * 192 + c];
#pragma unroll
        for (int m = 0; m < 8; m++) { float v = vl[m][c]; acc0[m] = fmaf(w0, v, acc0[m]); acc1[m] = fmaf(w1, v, acc1[m]); }
    }
    float s1a = 0, s2a = 0, s1b = 0, s2b = 0;
    for (int m = 0; m < 8; m++) {
        float ya = acc0[m], yb = acc1[m];
        y6[((size_t)b * M_ + m0 + m) * 512 + o0] = ya;
        y6[((size_t)b * M_ + m0 + m) * 512 + o1] = yb;
        s1a += ya; s2a = fmaf(ya, ya, s2a); s1b += yb; s2b = fmaf(yb, yb, s2b);
    }
    float* sp = stats + (blockIdx.x & 31) * 1024;
    atomicAdd(&sp[o0], s1a); atomicAdd(&sp[512 + o0], s2a);
    atomicAdd(&sp[o1], s1b); atomicAdd(&sp[512 + o1], s2b);
}

// ---------------------------------------------------------------- bn6+lrelu+max over M (parallel over m)
__global__ void k_maxM(const float* __restrict__ y6, const float* __restrict__ prm,
                       float* __restrict__ xgmax) {
    int blk = blockIdx.x;                 // b*16 + ochunk
    int b = blk >> 4;
    int o = ((blk & 15) << 5) + (threadIdx.x & 31);
    int mg = threadIdx.x >> 5;            // 8 m-groups
    float a = prm[o], sh = prm[512 + o];
    float mx = -1e30f;
    for (int m = mg; m < M_; m += 8)
        mx = fmaxf(mx, lrelu(fmaf(a, y6[((size_t)b * M_ + m) * 512 + o], sh)));
    __shared__ float red[256];
    red[threadIdx.x] = mx;
    __syncthreads();
    for (int s = 128; s >= 32; s >>= 1) {
        if (threadIdx.x < s) red[threadIdx.x] = fmaxf(red[threadIdx.x], red[threadIdx.x + s]);
        __syncthreads();
    }
    if (threadIdx.x < 32) xgmax[b * 512 + o] = red[threadIdx.x];
}

// ---------------------------------------------------------------- P7 = W7[:, :512] . xgmax
__global__ void k_p7(const float* __restrict__ xgmax, const float* __restrict__ W7,
                     float* __restrict__ p7) {
    int t = blockIdx.x * blockDim.x + threadIdx.x;
    if (t >= B_ * 128) return;
    int b = t / 128, o = t % 128;
    float acc = 0.f;
    for (int c = 0; c < 512; c++) acc = fmaf(W7[o * 704 + c], xgmax[b * 512 + c], acc);
    p7[t] = acc;
}

// ---------------------------------------------------------------- W7 conv (704->128), 192 variable
__global__ __launch_bounds__(256) void k_conv_w7(
    const float* __restrict__ x1t, const float* __restrict__ x2t,
    const float* __restrict__ x3t, const float* __restrict__ p7,
    const float* __restrict__ W7, float* __restrict__ y7, float* __restrict__ stats) {
    __shared__ float vl[16][192];
    int item0 = blockIdx.x * 16;
    for (int i = threadIdx.x; i < 16 * 192; i += 256) {
        int it = i / 192, c = i % 192;
        const float* src = c < 64 ? x1t : (c < 128 ? x2t : x3t);
        vl[it][c] = src[((size_t)(item0 + it)) * 64 + (c & 63)];
    }
    __syncthreads();
    int o = threadIdx.x & 127, h = threadIdx.x >> 7;
    float acc[8] = {0};
    for (int c = 0; c < 192; c++) {
        float w = W7[o * 704 + 512 + c];
#pragma unroll
        for (int i = 0; i < 8; i++) acc[i] = fmaf(w, vl[h * 8 + i][c], acc[i]);
    }
    float s1 = 0, s2 = 0;
    for (int i = 0; i < 8; i++) {
        int item = item0 + h * 8 + i;
        int b = item / N_;
        float yv = p7[b * 128 + o] + acc[i];
        y7[(size_t)item * 128 + o] = yv;
        s1 += yv; s2 = fmaf(yv, yv, s2);
    }
    __shared__ float r1[256], r2[256];
    r1[threadIdx.x] = s1; r2[threadIdx.x] = s2;
    __syncthreads();
    if (threadIdx.x < 128) {
        float* sp = stats + (blockIdx.x & 31) * 1024;
        atomicAdd(&sp[threadIdx.x], r1[threadIdx.x] + r1[threadIdx.x + 128]);
        atomicAdd(&sp[128 + threadIdx.x], r2[threadIdx.x] + r2[threadIdx.x + 128]);
    }
}

// ---------------------------------------------------------------- W8 conv (128->64)
__global__ __launch_bounds__(256) void k_conv_w8(
    const float* __restrict__ y7, const float* __restrict__ prm7,
    const float* __restrict__ W8, float* __restrict__ y8, float* __restrict__ stats) {
    int lane = threadIdx.x & 63;
    int item = blockIdx.x * 4 + (threadIdx.x >> 6);
    float W0[64], W1r[64];
#pragma unroll
    for (int c = 0; c < 64; c++) {
        W0[c] = W8[lane * 128 + c];
        W1r[c] = W8[lane * 128 + 64 + c];
    }
    float a0 = prm7[lane], sh0 = prm7[128 + lane];
    float a1 = prm7[64 + lane], sh1 = prm7[128 + 64 + lane];
    float z0 = lrelu(fmaf(a0, y7[(size_t)item * 128 + lane], sh0));
    float z1 = lrelu(fmaf(a1, y7[(size_t)item * 128 + 64 + lane], sh1));
    float acc = 0.f;
#pragma unroll
    for (int c = 0; c < 64; c++) {
        acc = fmaf(W0[c], __shfl(z0, c), acc);
        acc = fmaf(W1r[c], __shfl(z1, c), acc);
    }
    y8[(size_t)item * 64 + lane] = acc;
    STATS_REDUCE_64(acc, acc * acc, stats)
}

// ---------------------------------------------------------------- final: bn8+lrelu, W9 -> out
__global__ __launch_bounds__(256) void k_final(
    const float* __restrict__ y8, const float* __restrict__ prm8,
    const float* __restrict__ W9, void* __restrict__ out, const int* __restrict__ flag) {
    __shared__ float zl[2][64];
    int item0 = blockIdx.x * 2;
    if (threadIdx.x < 128) {
        int it = threadIdx.x >> 6, c = threadIdx.x & 63;
        float z = fmaf(prm8[c], y8[(size_t)(item0 + it) * 64 + c], prm8[64 + c]);
        zl[it][c] = lrelu(z);
    }
    __syncthreads();
    int it = threadIdx.x >> 7, o = threadIdx.x & 127;
    float acc = 0.f;
#pragma unroll
    for (int c = 0; c < 64; c++) acc = fmaf(W9[o * 64 + c], zl[it][c], acc);
    size_t oi = (size_t)(item0 + it) * 128 + o;
    if (*flag) ((bf16*)out)[oi] = __float2bfloat16(acc);
    else ((float*)out)[oi] = acc;
}

// ---------------------------------------------------------------- host
extern "C" void kernel_launch(void* const* d_in, const int* in_sizes, int n_in,
                              void* d_out, int out_size, void* d_ws, size_t ws_size,
                              hipStream_t stream) {
    (void)in_sizes; (void)n_in; (void)out_size; (void)ws_size;
    const void* x = d_in[0];
    const void* xgrid = d_in[1];
    const int* FPS = (const int*)d_in[2];

    char* ws = (char*)d_ws;
    size_t off = 0;
    auto alloc = [&](size_t bytes) -> char* {
        char* p = ws + off;
        off = (off + bytes + 255) & ~(size_t)255;
        return p;
    };
    int* flag    = (int*)alloc(256);
    float* stats = (float*)alloc(8 * 32 * 1024 * sizeof(float));   // 1 MB
    float* prm   = (float*)alloc(8 * 1024 * sizeof(float));
    static const int wsz[9] = {384, 4096, 8192, 4096, 8192, 98304, 90112, 8192, 8192};
    static const int dims[8] = {64, 64, 64, 64, 64, 512, 128, 64};
    float* cW[9];
    for (int i = 0; i < 9; i++) cW[i] = (float*)alloc((size_t)wsz[i] * 4);
    float* cG[8];
    float* cB[8];
    for (int j = 0; j < 8; j++) {
        cG[j] = (float*)alloc((size_t)dims[j] * 4);
        cB[j] = (float*)alloc((size_t)dims[j] * 4);
    }
    float* xt    = (float*)alloc((size_t)BN * 3 * 4);
    float* gt    = (float*)alloc((size_t)BM * 3 * 4);
    float* gT3   = (float*)alloc((size_t)B_ * 3 * M_ * 4);
    float* gn    = (float*)alloc((size_t)BM * 4);
    int* nearest = (int*)alloc((size_t)BN * 4);
    int* nbr     = (int*)alloc((size_t)BM * K_ * 4);
    float* Pg    = (float*)alloc((size_t)BM * 64 * 4);     // 256 KB
    float* x1t   = (float*)alloc((size_t)BN * 64 * 4);
    float* x2t   = (float*)alloc((size_t)BN * 64 * 4);
    float* x3t   = (float*)alloc((size_t)BN * 64 * 4);
    float* x1gt  = (float*)alloc((size_t)BM * 64 * 4);
    float* x2gt  = (float*)alloc((size_t)BM * 64 * 4);
    float* x3gt  = (float*)alloc((size_t)BM * 64 * 4);
    float* gT64  = (float*)alloc((size_t)B_ * 64 * M_ * 4);
    float* y6    = (float*)alloc((size_t)BM * 512 * 4);    // 2 MB
    float* xgmax = (float*)alloc((size_t)B_ * 512 * 4);
    float* p7    = (float*)alloc((size_t)B_ * 128 * 4);
    float* y7    = (float*)alloc((size_t)BN * 128 * 4);    // 4 MB
    float* y8    = (float*)alloc((size_t)BN * 64 * 4);     // 2 MB
    // Aliases (lifetimes verified: stage buffers dead before tail writes them):
    float* D0b = y7;                    // 2 MB (first half of y7)
    float* S0b = y7 + (size_t)BN * 64;  // 2 MB (second half)
    float* mnb = y8;                    // 2 MB
    float* mxb = y6;                    // 2 MB

    hipMemsetAsync(stats, 0, 8 * 32 * 1024 * sizeof(float), stream);
    k_detect<<<1, 256, 0, stream>>>((const unsigned short*)x, flag);

    CvtArgs ca;
    for (int i = 0; i < 9; i++) ca.d[i] = {d_in[3 + i], cW[i], wsz[i]};
    for (int j = 0; j < 8; j++) {
        ca.d[9 + 2 * j]     = {d_in[12 + 2 * j], cG[j], dims[j]};
        ca.d[9 + 2 * j + 1] = {d_in[13 + 2 * j], cB[j], dims[j]};
    }
    k_convert<<<dim3(384, 25), 256, 0, stream>>>(ca, flag);
    k_transpose<<<(BN + 255) / 256, 256, 0, stream>>>(x, xgrid, flag, xt, gt, gT3);

    const int PG = BN / 4;     // 2048 blocks, wave per point
    const int CK = BN * K_;

    // ---- stage A (D=3, W1,W2) ----
    k_gnorm<3><<<4, 256, 0, stream>>>(gt, gn);
    k_nearest3<<<(BN + 255) / 256, 256, 0, stream>>>(xt, gt, gn, nearest);
    k_nbr<3><<<BM / 4, 256, 0, stream>>>(gt, gT3, gn, nbr);
    k_pgrid<3><<<BM / 4, 256, 0, stream>>>(gt, cW[0], Pg);
    k_prep<3><<<PG, 256, 0, stream>>>(xt, cW[0], D0b, S0b);
    k_pass0<0><<<PG, 256, 0, stream>>>(Pg, D0b, S0b, nearest, nbr, stats + 0 * 32768, nullptr, nullptr);
    k_finalize<<<2, 256, 0, stream>>>(stats + 0 * 32768, 64, CK, cG[0], cB[0], prm + 0 * 1024);
    k_pass1<<<PG, 256, 0, stream>>>(Pg, D0b, S0b, nearest, nbr, prm + 0 * 1024, cW[1], stats + 1 * 32768, mnb, mxb);
    k_finalize<<<2, 256, 0, stream>>>(stats + 1 * 32768, 64, CK, cG[1], cB[1], prm + 1 * 1024);
    k_apply<<<BN * 64 / 256, 256, 0, stream>>>(mnb, mxb, prm + 1 * 1024, x1t);
    k_gather<<<BM, 64, 0, stream>>>(x1t, FPS, x1gt);

    // ---- stage B (D=64, W3,W4) ----
    k_gt64<<<BM * 64 / 256, 256, 0, stream>>>(x1gt, gT64);
    k_gnorm<64><<<4, 256, 0, stream>>>(x1gt, gn);
    k_nearest64<<<PG, 256, 0, stream>>>(x1t, gT64, gn, nearest);
    k_nbr<64><<<BM / 4, 256, 0, stream>>>(x1gt, gT64, gn, nbr);
    k_pgrid<64><<<BM / 4, 256, 0, stream>>>(x1gt, cW[2], Pg);
    k_prep<64><<<PG, 256, 0, stream>>>(x1t, cW[2], D0b, S0b);
    k_pass0<0><<<PG, 256, 0, stream>>>(Pg, D0b, S0b, nearest, nbr, stats + 2 * 32768, nullptr, nullptr);
    k_finalize<<<2, 256, 0, stream>>>(stats + 2 * 32768, 64, CK, cG[2], cB[2], prm + 2 * 1024);
    k_pass1<<<PG, 256, 0, stream>>>(Pg, D0b, S0b, nearest, nbr, prm + 2 * 1024, cW[3], stats + 3 * 32768, mnb, mxb);
    k_finalize<<<2, 256, 0, stream>>>(stats + 3 * 32768, 64, CK, cG[3], cB[3], prm + 3 * 1024);
    k_apply<<<BN * 64 / 256, 256, 0, stream>>>(mnb, mxb, prm + 3 * 1024, x2t);
    k_gather<<<BM, 64, 0, stream>>>(x2t, FPS, x2gt);

    // ---- stage C (D=64, W5 single conv) ----
    k_gt64<<<BM * 64 / 256, 256, 0, stream>>>(x2gt, gT64);
    k_gnorm<64><<<4, 256, 0, stream>>>(x2gt, gn);
    k_nearest64<<<PG, 256, 0, stream>>>(x2t, gT64, gn, nearest);
    k_nbr<64><<<BM / 4, 256, 0, stream>>>(x2gt, gT64, gn, nbr);
    k_pgrid<64><<<BM / 4, 256, 0, stream>>>(x2gt, cW[4], Pg);
    k_prep<64><<<PG, 256, 0, stream>>>(x2t, cW[4], D0b, S0b);
    k_pass0<1><<<PG, 256, 0, stream>>>(Pg, D0b, S0b, nearest, nbr, stats + 4 * 32768, mnb, mxb);
    k_finalize<<<2, 256, 0, stream>>>(stats + 4 * 32768, 64, CK, cG[4], cB[4], prm + 4 * 1024);
    k_apply<<<BN * 64 / 256, 256, 0, stream>>>(mnb, mxb, prm + 4 * 1024, x3t);
    k_gather<<<BM, 64, 0, stream>>>(x3t, FPS, x3gt);

    // ---- global MLP tail (mx/mn/D0/S0 dead from here; y6/y7/y8 reclaim storage) ----
    k_conv_w6<<<BM / 8, 256, 0, stream>>>(x1gt, x2gt, x3gt, cW[5], y6, stats + 5 * 32768);
    k_finalize<<<2, 256, 0, stream>>>(stats + 5 * 32768, 512, BM, cG[5], cB[5], prm + 5 * 1024);
    k_maxM<<<B_ * 16, 256, 0, stream>>>(y6, prm + 5 * 1024, xgmax);
    k_p7<<<1, 256, 0, stream>>>(xgmax, cW[6], p7);
    k_conv_w7<<<BN / 16, 256, 0, stream>>>(x1t, x2t, x3t, p7, cW[6], y7, stats + 6 * 32768);
    k_finalize<<<2, 256, 0, stream>>>(stats + 6 * 32768, 128, BN, cG[6], cB[6], prm + 6 * 1024);
    k_conv_w8<<<BN / 4, 256, 0, stream>>>(y7, prm + 6 * 1024, cW[7], y8, stats + 7 * 32768);
    k_finalize<<<2, 256, 0, stream>>>(stats + 7 * 32768, 64, BN, cG[7], cB[7], prm + 7 * 1024);
    k_final<<<BN / 2, 256, 0, stream>>>(y8, prm + 7 * 1024, cW[8], d_out, flag);
}